// Round 10
// baseline (251.145 us; speedup 1.0000x reference)
//
#include <hip/hip_runtime.h>
#include <hip/hip_bf16.h>
#include <hip/hip_fp8.h>

typedef __attribute__((ext_vector_type(4))) int i32x4;
typedef __attribute__((ext_vector_type(8))) int i32x8;
typedef __attribute__((ext_vector_type(16))) float f32x16;

#define MARGIN 0.3f
#define BIGF 3.0e38f

// lgkm-only barrier: syncs LDS traffic WITHOUT draining vmcnt, so the
// register-stage global loads stay in flight across it (the whole point).
#define BAR_LGKM() asm volatile("s_waitcnt lgkmcnt(0)\n\ts_barrier" ::: "memory")

// Wave-per-row convert: fp32 -> fp8 e4m3 (OCP) cast, fp32 row norm of the
// fp8-ROUNDED values (consistent with MFMA dots -> exact diagonal), init
// ap/an/cnt. 4 rows per 256-thread block. (R7/R8-verified.)
__global__ __launch_bounds__(256) void convert_norm_kernel(
    const float* __restrict__ X, unsigned char* __restrict__ Xq,
    float* __restrict__ nrm, unsigned* __restrict__ ap,
    unsigned* __restrict__ an, unsigned* __restrict__ cnt, int K) {
    const int wave = threadIdx.x >> 6, lane = threadIdx.x & 63;
    const int row = blockIdx.x * 4 + wave;
    const float* xr = X + (size_t)row * K;
    unsigned char* xqr = Xq + (size_t)row * K;
    float s = 0.0f;
    for (int c = lane * 8; c < K; c += 64 * 8) {
        float4 v0 = *(const float4*)(xr + c);
        float4 v1 = *(const float4*)(xr + c + 4);
        float f[8] = {v0.x, v0.y, v0.z, v0.w, v1.x, v1.y, v1.z, v1.w};
        union { unsigned char b[8]; uint2 u; } p;
#pragma unroll
        for (int i = 0; i < 8; i++) {
            __hip_fp8_e4m3 q(f[i]);       // OCP e4m3, RNE+saturate
            p.b[i] = q.__x;
            float d = (float)q;           // decoded value
            s += d * d;
        }
        *(uint2*)(xqr + c) = p.u;
    }
    for (int off = 32; off > 0; off >>= 1) s += __shfl_xor(s, off, 64);
    if (lane == 0) {
        nrm[row] = s;
        ap[row] = 0u;           // dist_ap >= 0 always (self is a positive)
        an[row] = 0x7F800000u;  // +inf
        if (row == 0) *cnt = 0u;
    }
}

// R7 geometry (best measured: 64x128 triangle tiles, 1056 blocks, 4 waves,
// BK=128, 24 KB single LDS buffer, XOR swizzle) + REGISTER-STAGE pipeline:
// tile t+1 is loaded global->VGPR at iteration start (in flight during
// compute of tile t), then ds_written to the SAME LDS buffer after an
// lgkm-only barrier. The vmem wait (compiler-inserted before the ds_write's
// first VGPR use) lands AFTER compute, so L2/L3 latency overlaps MFMA
// instead of being drained at a vmcnt(0) barrier (the R7/R8 critical path).
// LDS size and occupancy unchanged vs R7 (the R4 lesson: occupancy first).
// All math R7/R8-verified: mfma_scale_f32_32x32x64_f8f6f4 with unit scales
// (0x7F), C/D map col=lane&31 / row=(reg&3)+8*(reg>>2)+4*(lane>>5),
// epilogue reductions, monotone uint atomics, fused last-block loss.
__global__ __launch_bounds__(256) void gemm_reduce_kernel(
    const unsigned char* __restrict__ Xq, const float* __restrict__ nrm,
    const int* __restrict__ Y, unsigned* __restrict__ ap,
    unsigned* __restrict__ an, unsigned* __restrict__ cnt,
    float* __restrict__ out, int N, int K) {
    __shared__ __align__(16) unsigned char sA[64 * 128];   // 8 KB
    __shared__ __align__(16) unsigned char sB[128 * 128];  // 16 KB
    __shared__ int sYr[64], sYc[128];
    __shared__ float sNr[64], sNc[128];
    __shared__ float redmax[4][64], redmin[4][64];
    __shared__ float lsum[4];
    __shared__ unsigned s_done;

    const int tid = threadIdx.x;
    const int wave = tid >> 6;
    const int lane = tid & 63;
    const int m = lane & 31;   // row within 32x32 subtile / col within wave tile
    const int h = lane >> 5;   // k-half (inputs) / row-group (outputs)

    // Decode (col-block j, row-block r): blocks for col j are j(j+1)..(j+1)(j+2).
    int j = 0;
    {
        const int b = blockIdx.x;
        while ((j + 1) * (j + 2) <= b) j++;
    }
    const int r = blockIdx.x - j * (j + 1);  // 0..2j+1
    const int rowBase = r * 64;
    const int colBase = j * 128;

    if (tid < 64) {
        sYr[tid] = Y[rowBase + tid];
        sNr[tid] = nrm[rowBase + tid];
    } else if (tid < 192) {
        int t = tid - 64;
        sYc[t] = Y[colBase + t];
        sNc[t] = nrm[colBase + t];
    }

    f32x16 acc[2];
#pragma unroll
    for (int si = 0; si < 2; si++)
#pragma unroll
        for (int rr = 0; rr < 16; rr++) acc[si][rr] = 0.0f;

    // Staging lane math (R7-verified): lane l covers LDS row l>>3 of an
    // 8-row group, physical 16B chunk l&7, holding LOGICAL chunk
    // (l&7)^(l>>3) so phys = logical ^ (row&7).
    const int rsub = lane >> 3;
    const int jchunk = (lane & 7) ^ rsub;
    const unsigned char* gA = Xq + (size_t)(rowBase + wave * 16 + rsub) * K + jchunk * 16;
    const unsigned char* gB = Xq + (size_t)(colBase + wave * 32 + rsub) * K + jchunk * 16;
    unsigned char* lA = sA + wave * 2048 + lane * 16;  // this thread's slots
    unsigned char* lB = sB + wave * 4096 + lane * 16;
    const size_t g8 = (size_t)8 * K;  // 8 rows, bytes

    const int e = m & 7;     // unswizzle key: row&7 = m&7 (row offsets are mult of 32)
    const int nit = K >> 7;  // BK=128

    uint4 pa[2], pb[4];  // register stage for the next tile
#define LOADT(it)                                                   \
    {                                                               \
        const size_t go = (size_t)(it) * 128;                       \
        pa[0] = *(const uint4*)(gA + go);                           \
        pa[1] = *(const uint4*)(gA + go + g8);                      \
        pb[0] = *(const uint4*)(gB + go);                           \
        pb[1] = *(const uint4*)(gB + go + g8);                      \
        pb[2] = *(const uint4*)(gB + go + 2 * g8);                  \
        pb[3] = *(const uint4*)(gB + go + 3 * g8);                  \
    }
#define WRITET()                                                    \
    {                                                               \
        *(uint4*)(lA) = pa[0];                                      \
        *(uint4*)(lA + 1024) = pa[1];                               \
        *(uint4*)(lB) = pb[0];                                      \
        *(uint4*)(lB + 1024) = pb[1];                               \
        *(uint4*)(lB + 2048) = pb[2];                               \
        *(uint4*)(lB + 3072) = pb[3];                               \
    }

    // Prologue: tile 0 regs -> LDS, make visible.
    LOADT(0);
    WRITET();
    BAR_LGKM();

    for (int it = 0; it < nit; it++) {
        const bool more = (it + 1 < nit);
        if (more) LOADT(it + 1);  // in flight during this iter's compute

#pragma unroll
        for (int s = 0; s < 2; s++) {      // two k64 steps per BK=128
            const int c0 = s * 4 + h * 2;  // logical 16B chunk of this k-half
            i32x8 af[2], bf;
#pragma unroll
            for (int si = 0; si < 2; si++) {
                const unsigned char* base = sA + (si * 32 + m) * 128;
                i32x4 lo = *(const i32x4*)(base + ((c0 ^ e) * 16));
                i32x4 hi = *(const i32x4*)(base + (((c0 + 1) ^ e) * 16));
                af[si] = __builtin_shufflevector(lo, hi, 0, 1, 2, 3, 4, 5, 6, 7);
            }
            {
                const unsigned char* base = sB + (wave * 32 + m) * 128;
                i32x4 lo = *(const i32x4*)(base + ((c0 ^ e) * 16));
                i32x4 hi = *(const i32x4*)(base + (((c0 + 1) ^ e) * 16));
                bf = __builtin_shufflevector(lo, hi, 0, 1, 2, 3, 4, 5, 6, 7);
            }
#pragma unroll
            for (int si = 0; si < 2; si++)
                acc[si] = __builtin_amdgcn_mfma_scale_f32_32x32x64_f8f6f4(
                    af[si], bf, acc[si], 0 /*A fmt fp8*/, 0 /*B fmt fp8*/,
                    0, 127 /*scale A = 2^0*/, 0, 127 /*scale B = 2^0*/);
        }

        if (more) {
            BAR_LGKM();  // all waves done READING the buffer (no vmem drain)
            WRITET();    // compiler waits on pa/pb here — after compute
            BAR_LGKM();  // writes visible before next iter's reads
        }
    }

    // Epilogue. C/D: col = m (within wave's 32 cols), row64 = si*32 +
    // (reg&3) + 8*(reg>>2) + 4*h.
    const int col = wave * 32 + m;
    const int yc = sYc[col];
    const float ncol = sNc[col];
    float cmx = -1.0f, cmn = BIGF;

#pragma unroll
    for (int si = 0; si < 2; si++)
#pragma unroll
        for (int reg = 0; reg < 16; reg++) {
            const int row64 = si * 32 + (reg & 3) + 8 * (reg >> 2) + 4 * h;
            float d2 = sNr[row64] + ncol - 2.0f * acc[si][reg];
            float d = sqrtf(fmaxf(d2, 0.0f));
            bool same = (sYr[row64] == yc);
            float dp = same ? d : -1.0f;
            float dn = same ? BIGF : d;
            cmx = fmaxf(cmx, dp);
            cmn = fminf(cmn, dn);
            // Row-side: reduce over the 32 col-lanes (offsets 1..16 keep h).
            float mx = dp, mn = dn;
            for (int off = 1; off < 32; off <<= 1) {
                mx = fmaxf(mx, __shfl_xor(mx, off, 64));
                mn = fminf(mn, __shfl_xor(mn, off, 64));
            }
            if (m == 0) {  // lanes 0 (h=0) and 32 (h=1): disjoint row64 sets
                redmax[wave][row64] = mx;
                redmin[wave][row64] = mn;
            }
        }

    // Col-side: merge the two h row-groups; lanes h==0 hold their col.
    cmx = fmaxf(cmx, __shfl_xor(cmx, 32, 64));
    cmn = fminf(cmn, __shfl_xor(cmn, 32, 64));
    if (h == 0) {
        atomicMax(&ap[colBase + col], __float_as_uint(fmaxf(cmx, 0.0f)));
        atomicMin(&an[colBase + col], __float_as_uint(cmn));
    }
    __syncthreads();

    // Row-side: combine 4 waves (non-negative floats: uint cmp == float cmp;
    // clamp max to 0 since true dist_ap >= 0 via the diagonal self-pair).
    if (tid < 64) {
        float mx = fmaxf(fmaxf(redmax[0][tid], redmax[1][tid]),
                         fmaxf(redmax[2][tid], redmax[3][tid]));
        float mn = fminf(fminf(redmin[0][tid], redmin[1][tid]),
                         fminf(redmin[2][tid], redmin[3][tid]));
        atomicMax(&ap[rowBase + tid], __float_as_uint(fmaxf(mx, 0.0f)));
        atomicMin(&an[rowBase + tid], __float_as_uint(mn));
    }

    // Last block computes the loss (release fence before counter increment;
    // acquire fence + agent-scope atomic loads in the last block).
    __syncthreads();
    if (tid == 0) {
        __threadfence();
        s_done = atomicAdd(cnt, 1u);
    }
    __syncthreads();
    if (s_done == gridDim.x - 1) {
        __threadfence();
        float s = 0.0f;
        for (int i = tid; i < N; i += 256) {
            unsigned ua = __hip_atomic_load(&ap[i], __ATOMIC_RELAXED,
                                            __HIP_MEMORY_SCOPE_AGENT);
            unsigned ub = __hip_atomic_load(&an[i], __ATOMIC_RELAXED,
                                            __HIP_MEMORY_SCOPE_AGENT);
            s += fmaxf(__uint_as_float(ua) - __uint_as_float(ub) + MARGIN, 0.0f);
        }
        for (int off = 32; off > 0; off >>= 1) s += __shfl_xor(s, off, 64);
        if (lane == 0) lsum[wave] = s;
        __syncthreads();
        if (tid == 0)
            out[0] = (lsum[0] + lsum[1] + lsum[2] + lsum[3]) / (float)N;
    }
}

extern "C" void kernel_launch(void* const* d_in, const int* in_sizes, int n_in,
                              void* d_out, int out_size, void* d_ws, size_t ws_size,
                              hipStream_t stream) {
    const float* X = (const float*)d_in[0];
    const int* Y = (const int*)d_in[1];
    float* out = (float*)d_out;
    const int N = in_sizes[1];          // 4096
    const int K = in_sizes[0] / N;      // 2048

    char* ws = (char*)d_ws;
    unsigned char* Xq = (unsigned char*)ws;                         // N*K bytes
    float* nrm = (float*)(ws + (size_t)N * K);
    unsigned* ap = (unsigned*)((char*)nrm + (size_t)N * 4);
    unsigned* an = (unsigned*)((char*)ap + (size_t)N * 4);
    unsigned* cnt = (unsigned*)((char*)an + (size_t)N * 4);

    convert_norm_kernel<<<N / 4, 256, 0, stream>>>(X, Xq, nrm, ap, an, cnt, K);
    const int NB = N / 128;
    const int nblocks = NB * (NB + 1);  // 64x128 tiles covering the triangle
    gemm_reduce_kernel<<<nblocks, 256, 0, stream>>>(Xq, nrm, Y, ap, an, cnt,
                                                    out, N, K);
}

// Round 11
// 146.898 us; speedup vs baseline: 1.7097x; 1.7097x over previous
//
#include <hip/hip_runtime.h>
#include <hip/hip_bf16.h>
#include <hip/hip_fp8.h>

typedef __attribute__((ext_vector_type(4))) int i32x4;
typedef __attribute__((ext_vector_type(8))) int i32x8;
typedef __attribute__((ext_vector_type(16))) float f32x16;

#define MARGIN 0.3f
#define BIGF 3.0e38f

// lgkm-only barrier: syncs LDS traffic WITHOUT draining vmcnt, so the
// register-stage global loads stay in flight across it.
#define BAR_LGKM() asm volatile("s_waitcnt lgkmcnt(0)\n\ts_barrier" ::: "memory")

// Wave-per-row convert: fp32 -> fp8 e4m3 (OCP) cast, fp32 row norm of the
// fp8-ROUNDED values (consistent with MFMA dots -> exact diagonal), init
// ap/an/cnt. 4 rows per 256-thread block. (R7/R8-verified.)
__global__ __launch_bounds__(256) void convert_norm_kernel(
    const float* __restrict__ X, unsigned char* __restrict__ Xq,
    float* __restrict__ nrm, unsigned* __restrict__ ap,
    unsigned* __restrict__ an, unsigned* __restrict__ cnt, int K) {
    const int wave = threadIdx.x >> 6, lane = threadIdx.x & 63;
    const int row = blockIdx.x * 4 + wave;
    const float* xr = X + (size_t)row * K;
    unsigned char* xqr = Xq + (size_t)row * K;
    float s = 0.0f;
    for (int c = lane * 8; c < K; c += 64 * 8) {
        float4 v0 = *(const float4*)(xr + c);
        float4 v1 = *(const float4*)(xr + c + 4);
        float f[8] = {v0.x, v0.y, v0.z, v0.w, v1.x, v1.y, v1.z, v1.w};
        union { unsigned char b[8]; uint2 u; } p;
#pragma unroll
        for (int i = 0; i < 8; i++) {
            __hip_fp8_e4m3 q(f[i]);       // OCP e4m3, RNE+saturate
            p.b[i] = q.__x;
            float d = (float)q;           // decoded value
            s += d * d;
        }
        *(uint2*)(xqr + c) = p.u;
    }
    for (int off = 32; off > 0; off >>= 1) s += __shfl_xor(s, off, 64);
    if (lane == 0) {
        nrm[row] = s;
        ap[row] = 0u;           // dist_ap >= 0 always (self is a positive)
        an[row] = 0x7F800000u;  // +inf
        if (row == 0) *cnt = 0u;
    }
}

// R7 geometry (best measured: 64x128 triangle tiles, 1056 blocks, 4 waves,
// BK=128, 24 KB single LDS buffer, XOR swizzle) + register-stage pipeline,
// SPILL-PROOFED (R10 post-mortem: uint4 ARRAYS + macros went to scratch —
// VGPR stayed 64, WRITE_SIZE hit 369 MB). Here the stage is six NAMED
// uint4 locals assigned straight-line; the last iteration is peeled so the
// loop body has no divergent load guard. Tile t+1 is loaded global->VGPR
// before computing tile t; after an lgkm-only barrier the ds_writes flush
// the stage (the compiler's vmcnt wait lands there — AFTER compute), so
// L2/L3 latency overlaps MFMA instead of draining at a vmcnt(0) barrier.
// All math R7/R8-verified: mfma_scale_f32_32x32x64_f8f6f4 with unit scales
// (0x7F), C/D map col=lane&31 / row=(reg&3)+8*(reg>>2)+4*(lane>>5),
// epilogue reductions, monotone uint atomics, fused last-block loss.
__global__ __launch_bounds__(256) void gemm_reduce_kernel(
    const unsigned char* __restrict__ Xq, const float* __restrict__ nrm,
    const int* __restrict__ Y, unsigned* __restrict__ ap,
    unsigned* __restrict__ an, unsigned* __restrict__ cnt,
    float* __restrict__ out, int N, int K) {
    __shared__ __align__(16) unsigned char sA[64 * 128];   // 8 KB
    __shared__ __align__(16) unsigned char sB[128 * 128];  // 16 KB
    __shared__ int sYr[64], sYc[128];
    __shared__ float sNr[64], sNc[128];
    __shared__ float redmax[4][64], redmin[4][64];
    __shared__ float lsum[4];
    __shared__ unsigned s_done;

    const int tid = threadIdx.x;
    const int wave = tid >> 6;
    const int lane = tid & 63;
    const int m = lane & 31;   // row within 32x32 subtile / col within wave tile
    const int h = lane >> 5;   // k-half (inputs) / row-group (outputs)

    // Decode (col-block j, row-block r): blocks for col j are j(j+1)..(j+1)(j+2).
    int j = 0;
    {
        const int b = blockIdx.x;
        while ((j + 1) * (j + 2) <= b) j++;
    }
    const int r = blockIdx.x - j * (j + 1);  // 0..2j+1
    const int rowBase = r * 64;
    const int colBase = j * 128;

    if (tid < 64) {
        sYr[tid] = Y[rowBase + tid];
        sNr[tid] = nrm[rowBase + tid];
    } else if (tid < 192) {
        int t = tid - 64;
        sYc[t] = Y[colBase + t];
        sNc[t] = nrm[colBase + t];
    }

    f32x16 acc[2];
#pragma unroll
    for (int si = 0; si < 2; si++)
#pragma unroll
        for (int rr = 0; rr < 16; rr++) acc[si][rr] = 0.0f;

    // Staging lane math (R7-verified): lane l covers LDS row l>>3 of an
    // 8-row group, physical 16B chunk l&7, holding LOGICAL chunk
    // (l&7)^(l>>3) so phys = logical ^ (row&7).
    const int rsub = lane >> 3;
    const int jchunk = (lane & 7) ^ rsub;
    const unsigned char* gA = Xq + (size_t)(rowBase + wave * 16 + rsub) * K + jchunk * 16;
    const unsigned char* gB = Xq + (size_t)(colBase + wave * 32 + rsub) * K + jchunk * 16;
    unsigned char* lA = sA + wave * 2048 + lane * 16;  // this thread's slots
    unsigned char* lB = sB + wave * 4096 + lane * 16;
    const size_t g8 = (size_t)8 * K;  // 8 rows, bytes

    const int e = m & 7;     // unswizzle key: row&7 = m&7 (row offsets are mult of 32)
    const int nit = K >> 7;  // BK=128 (16 iters at K=2048)

    // Named register stage — NO arrays (R10's scratch trap).
    uint4 p0, p1, p2, p3, p4, p5;

    // Prologue: tile 0 -> regs -> LDS, make visible.
    p0 = *(const uint4*)(gA);
    p1 = *(const uint4*)(gA + g8);
    p2 = *(const uint4*)(gB);
    p3 = *(const uint4*)(gB + g8);
    p4 = *(const uint4*)(gB + 2 * g8);
    p5 = *(const uint4*)(gB + 3 * g8);
    *(uint4*)(lA) = p0;
    *(uint4*)(lA + 1024) = p1;
    *(uint4*)(lB) = p2;
    *(uint4*)(lB + 1024) = p3;
    *(uint4*)(lB + 2048) = p4;
    *(uint4*)(lB + 3072) = p5;
    BAR_LGKM();

    for (int it = 0; it < nit - 1; it++) {
        // Issue next tile's loads — in flight during this iter's compute.
        const size_t go = (size_t)(it + 1) * 128;
        p0 = *(const uint4*)(gA + go);
        p1 = *(const uint4*)(gA + go + g8);
        p2 = *(const uint4*)(gB + go);
        p3 = *(const uint4*)(gB + go + g8);
        p4 = *(const uint4*)(gB + go + 2 * g8);
        p5 = *(const uint4*)(gB + go + 3 * g8);

#pragma unroll
        for (int s = 0; s < 2; s++) {      // two k64 steps per BK=128
            const int c0 = s * 4 + h * 2;  // logical 16B chunk of this k-half
            i32x8 af[2], bf;
#pragma unroll
            for (int si = 0; si < 2; si++) {
                const unsigned char* base = sA + (si * 32 + m) * 128;
                i32x4 lo = *(const i32x4*)(base + ((c0 ^ e) * 16));
                i32x4 hi = *(const i32x4*)(base + (((c0 + 1) ^ e) * 16));
                af[si] = __builtin_shufflevector(lo, hi, 0, 1, 2, 3, 4, 5, 6, 7);
            }
            {
                const unsigned char* base = sB + (wave * 32 + m) * 128;
                i32x4 lo = *(const i32x4*)(base + ((c0 ^ e) * 16));
                i32x4 hi = *(const i32x4*)(base + (((c0 + 1) ^ e) * 16));
                bf = __builtin_shufflevector(lo, hi, 0, 1, 2, 3, 4, 5, 6, 7);
            }
#pragma unroll
            for (int si = 0; si < 2; si++)
                acc[si] = __builtin_amdgcn_mfma_scale_f32_32x32x64_f8f6f4(
                    af[si], bf, acc[si], 0 /*A fmt fp8*/, 0 /*B fmt fp8*/,
                    0, 127 /*scale A = 2^0*/, 0, 127 /*scale B = 2^0*/);
        }

        BAR_LGKM();  // all waves done READING the buffer (no vmem drain)
        // Flush stage -> LDS; compiler inserts s_waitcnt vmcnt here (after
        // compute), which is the whole point.
        *(uint4*)(lA) = p0;
        *(uint4*)(lA + 1024) = p1;
        *(uint4*)(lB) = p2;
        *(uint4*)(lB + 1024) = p3;
        *(uint4*)(lB + 2048) = p4;
        *(uint4*)(lB + 3072) = p5;
        BAR_LGKM();  // writes visible before next iter's reads
    }

    // Peeled last iteration: compute only.
#pragma unroll
    for (int s = 0; s < 2; s++) {
        const int c0 = s * 4 + h * 2;
        i32x8 af[2], bf;
#pragma unroll
        for (int si = 0; si < 2; si++) {
            const unsigned char* base = sA + (si * 32 + m) * 128;
            i32x4 lo = *(const i32x4*)(base + ((c0 ^ e) * 16));
            i32x4 hi = *(const i32x4*)(base + (((c0 + 1) ^ e) * 16));
            af[si] = __builtin_shufflevector(lo, hi, 0, 1, 2, 3, 4, 5, 6, 7);
        }
        {
            const unsigned char* base = sB + (wave * 32 + m) * 128;
            i32x4 lo = *(const i32x4*)(base + ((c0 ^ e) * 16));
            i32x4 hi = *(const i32x4*)(base + (((c0 + 1) ^ e) * 16));
            bf = __builtin_shufflevector(lo, hi, 0, 1, 2, 3, 4, 5, 6, 7);
        }
#pragma unroll
        for (int si = 0; si < 2; si++)
            acc[si] = __builtin_amdgcn_mfma_scale_f32_32x32x64_f8f6f4(
                af[si], bf, acc[si], 0, 0, 0, 127, 0, 127);
    }

    // Epilogue. C/D: col = m (within wave's 32 cols), row64 = si*32 +
    // (reg&3) + 8*(reg>>2) + 4*h.
    const int col = wave * 32 + m;
    const int yc = sYc[col];
    const float ncol = sNc[col];
    float cmx = -1.0f, cmn = BIGF;

#pragma unroll
    for (int si = 0; si < 2; si++)
#pragma unroll
        for (int reg = 0; reg < 16; reg++) {
            const int row64 = si * 32 + (reg & 3) + 8 * (reg >> 2) + 4 * h;
            float d2 = sNr[row64] + ncol - 2.0f * acc[si][reg];
            float d = sqrtf(fmaxf(d2, 0.0f));
            bool same = (sYr[row64] == yc);
            float dp = same ? d : -1.0f;
            float dn = same ? BIGF : d;
            cmx = fmaxf(cmx, dp);
            cmn = fminf(cmn, dn);
            // Row-side: reduce over the 32 col-lanes (offsets 1..16 keep h).
            float mx = dp, mn = dn;
            for (int off = 1; off < 32; off <<= 1) {
                mx = fmaxf(mx, __shfl_xor(mx, off, 64));
                mn = fminf(mn, __shfl_xor(mn, off, 64));
            }
            if (m == 0) {  // lanes 0 (h=0) and 32 (h=1): disjoint row64 sets
                redmax[wave][row64] = mx;
                redmin[wave][row64] = mn;
            }
        }

    // Col-side: merge the two h row-groups; lanes h==0 hold their col.
    cmx = fmaxf(cmx, __shfl_xor(cmx, 32, 64));
    cmn = fminf(cmn, __shfl_xor(cmn, 32, 64));
    if (h == 0) {
        atomicMax(&ap[colBase + col], __float_as_uint(fmaxf(cmx, 0.0f)));
        atomicMin(&an[colBase + col], __float_as_uint(cmn));
    }
    __syncthreads();

    // Row-side: combine 4 waves (non-negative floats: uint cmp == float cmp;
    // clamp max to 0 since true dist_ap >= 0 via the diagonal self-pair).
    if (tid < 64) {
        float mx = fmaxf(fmaxf(redmax[0][tid], redmax[1][tid]),
                         fmaxf(redmax[2][tid], redmax[3][tid]));
        float mn = fminf(fminf(redmin[0][tid], redmin[1][tid]),
                         fminf(redmin[2][tid], redmin[3][tid]));
        atomicMax(&ap[rowBase + tid], __float_as_uint(fmaxf(mx, 0.0f)));
        atomicMin(&an[rowBase + tid], __float_as_uint(mn));
    }

    // Last block computes the loss (release fence before counter increment;
    // acquire fence + agent-scope atomic loads in the last block).
    __syncthreads();
    if (tid == 0) {
        __threadfence();
        s_done = atomicAdd(cnt, 1u);
    }
    __syncthreads();
    if (s_done == gridDim.x - 1) {
        __threadfence();
        float s = 0.0f;
        for (int i = tid; i < N; i += 256) {
            unsigned ua = __hip_atomic_load(&ap[i], __ATOMIC_RELAXED,
                                            __HIP_MEMORY_SCOPE_AGENT);
            unsigned ub = __hip_atomic_load(&an[i], __ATOMIC_RELAXED,
                                            __HIP_MEMORY_SCOPE_AGENT);
            s += fmaxf(__uint_as_float(ua) - __uint_as_float(ub) + MARGIN, 0.0f);
        }
        for (int off = 32; off > 0; off >>= 1) s += __shfl_xor(s, off, 64);
        if (lane == 0) lsum[wave] = s;
        __syncthreads();
        if (tid == 0)
            out[0] = (lsum[0] + lsum[1] + lsum[2] + lsum[3]) / (float)N;
    }
}

extern "C" void kernel_launch(void* const* d_in, const int* in_sizes, int n_in,
                              void* d_out, int out_size, void* d_ws, size_t ws_size,
                              hipStream_t stream) {
    const float* X = (const float*)d_in[0];
    const int* Y = (const int*)d_in[1];
    float* out = (float*)d_out;
    const int N = in_sizes[1];          // 4096
    const int K = in_sizes[0] / N;      // 2048

    char* ws = (char*)d_ws;
    unsigned char* Xq = (unsigned char*)ws;                         // N*K bytes
    float* nrm = (float*)(ws + (size_t)N * K);
    unsigned* ap = (unsigned*)((char*)nrm + (size_t)N * 4);
    unsigned* an = (unsigned*)((char*)ap + (size_t)N * 4);
    unsigned* cnt = (unsigned*)((char*)an + (size_t)N * 4);

    convert_norm_kernel<<<N / 4, 256, 0, stream>>>(X, Xq, nrm, ap, an, cnt, K);
    const int NB = N / 128;
    const int nblocks = NB * (NB + 1);  // 64x128 tiles covering the triangle
    gemm_reduce_kernel<<<nblocks, 256, 0, stream>>>(Xq, nrm, Y, ap, an, cnt,
                                                    out, N, K);
}

// Round 12
// 133.202 us; speedup vs baseline: 1.8854x; 1.1028x over previous
//
#include <hip/hip_runtime.h>
#include <hip/hip_bf16.h>
#include <hip/hip_fp8.h>

typedef __attribute__((ext_vector_type(4))) int i32x4;
typedef __attribute__((ext_vector_type(8))) int i32x8;
typedef __attribute__((ext_vector_type(16))) float f32x16;

#define MARGIN 0.3f
#define BIGF 3.0e38f

__device__ __forceinline__ void gl2lds16(const void* g, void* l) {
    __builtin_amdgcn_global_load_lds(
        (const __attribute__((address_space(1))) void*)g,
        (__attribute__((address_space(3))) void*)l,
        16, 0, 0);
}

// Wave-per-row convert: fp32 -> fp8 e4m3 (OCP) cast, fp32 row norm of the
// fp8-ROUNDED values (consistent with MFMA dots -> exact diagonal), init
// ap/an/cnt. 4 rows per 256-thread block. (R7/R8/R11-verified.)
__global__ __launch_bounds__(256) void convert_norm_kernel(
    const float* __restrict__ X, unsigned char* __restrict__ Xq,
    float* __restrict__ nrm, unsigned* __restrict__ ap,
    unsigned* __restrict__ an, unsigned* __restrict__ cnt, int K) {
    const int wave = threadIdx.x >> 6, lane = threadIdx.x & 63;
    const int row = blockIdx.x * 4 + wave;
    const float* xr = X + (size_t)row * K;
    unsigned char* xqr = Xq + (size_t)row * K;
    float s = 0.0f;
    for (int c = lane * 8; c < K; c += 64 * 8) {
        float4 v0 = *(const float4*)(xr + c);
        float4 v1 = *(const float4*)(xr + c + 4);
        float f[8] = {v0.x, v0.y, v0.z, v0.w, v1.x, v1.y, v1.z, v1.w};
        union { unsigned char b[8]; uint2 u; } p;
#pragma unroll
        for (int i = 0; i < 8; i++) {
            __hip_fp8_e4m3 q(f[i]);       // OCP e4m3, RNE+saturate
            p.b[i] = q.__x;
            float d = (float)q;           // decoded value
            s += d * d;
        }
        *(uint2*)(xqr + c) = p.u;
    }
    for (int off = 32; off > 0; off >>= 1) s += __shfl_xor(s, off, 64);
    if (lane == 0) {
        nrm[row] = s;
        ap[row] = 0u;           // dist_ap >= 0 always (self is a positive)
        an[row] = 0x7F800000u;  // +inf
        if (row == 0) *cnt = 0u;
    }
}

// FULL-SQUARE fp8-MX GEMM-reduce in the m148 shape: 128x128 tiles ->
// EXACTLY 1024 blocks = 4.0 blocks/CU (the R7 triangle's 1056 blocks had a
// 25% tail: 32 CUs ran a 5th block while 224 idled; symmetry saved 1.9x
// FLOPs but cost 2x staged-bytes/output + 2x barriers/output + the tail —
// net negative, so the triangle is dropped). 4 waves (2x2), wave tile
// 64x64 = 2x2 subtiles of 32x32x64 mfma_scale (unit scales 0x7F): 8 MFMA +
// 16 ds_read_b128 per wave-iter, 32 KB staged/iter, BK=128, 16 iters.
// Full G means the epilogue needs ROW-side reduction only ((j,i) lives in
// the transposed block). All pieces R7/R8/R11-verified: staging lane math
// + XOR swizzle (phys 16B chunk = logical ^ (row&7)), C/D map col=lane&31,
// row=(reg&3)+8*(reg>>2)+4*(lane>>5), monotone uint atomics, fused
// last-block loss. __launch_bounds__(256,4) caps VGPR at 128 so 4 blocks
// (16 waves) stay resident per CU.
__global__ __launch_bounds__(256, 4) void gemm_reduce_kernel(
    const unsigned char* __restrict__ Xq, const float* __restrict__ nrm,
    const int* __restrict__ Y, unsigned* __restrict__ ap,
    unsigned* __restrict__ an, unsigned* __restrict__ cnt,
    float* __restrict__ out, int N, int K) {
    __shared__ __align__(16) unsigned char sA[128 * 128];  // 16 KB
    __shared__ __align__(16) unsigned char sB[128 * 128];  // 16 KB
    __shared__ int sYr[128], sYc[128];
    __shared__ float sNr[128], sNc[128];
    __shared__ float redmax[4][64], redmin[4][64];
    __shared__ float lsum[4];
    __shared__ unsigned s_done;

    const int tid = threadIdx.x;
    const int wave = tid >> 6;
    const int lane = tid & 63;
    const int m = lane & 31;   // row within 32x32 subtile / col within subtile
    const int h = lane >> 5;   // k-half (inputs) / row-group (outputs)
    const int wr = wave >> 1;  // wave row (0..1): rows wr*64..+63
    const int wc = wave & 1;   // wave col (0..1): cols wc*64..+63

    const int NB = N >> 7;  // 32
    const int rowBase = (blockIdx.x >> 5) * 128;
    const int colBase = (blockIdx.x & (NB - 1)) * 128;

    if (tid < 128) {
        sYr[tid] = Y[rowBase + tid];
        sNr[tid] = nrm[rowBase + tid];
    } else {
        int t = tid - 128;
        sYc[t] = Y[colBase + t];
        sNc[t] = nrm[colBase + t];
    }

    f32x16 acc[2][2];
#pragma unroll
    for (int si = 0; si < 2; si++)
#pragma unroll
        for (int sj = 0; sj < 2; sj++)
#pragma unroll
            for (int rr = 0; rr < 16; rr++) acc[si][sj][rr] = 0.0f;

    // Staging (R7-verified lane math): lane l covers LDS row l>>3 of an
    // 8-row group, physical 16B chunk l&7, fetching LOGICAL chunk
    // (l&7)^(l>>3) so phys = logical ^ (row&7). Each wave stages its own
    // 32 rows of A and of B (4 gl2lds each, 1 KB per gl2lds).
    const int rsub = lane >> 3;
    const int jchunk = (lane & 7) ^ rsub;
    const unsigned char* gA = Xq + (size_t)(rowBase + wave * 32 + rsub) * K + jchunk * 16;
    const unsigned char* gB = Xq + (size_t)(colBase + wave * 32 + rsub) * K + jchunk * 16;
    unsigned char* lA = sA + wave * 4096;  // 32 rows * 128 B
    unsigned char* lB = sB + wave * 4096;
    const size_t g8 = (size_t)8 * K;  // 8 rows, bytes

    const int e = m & 7;     // unswizzle key: row&7 = m&7 (row offsets are mult of 32)
    const int nit = K >> 7;  // BK=128 (16 iters at K=2048)

    for (int it = 0; it < nit; it++) {
        const size_t go = (size_t)it * 128;  // 128 k-elems * 1 B
#pragma unroll
        for (int g = 0; g < 4; g++) {
            gl2lds16(gA + go + g * g8, lA + g * 1024);
            gl2lds16(gB + go + g * g8, lB + g * 1024);
        }
        __syncthreads();  // drains vmcnt for gl2lds

#pragma unroll
        for (int s = 0; s < 2; s++) {      // two k64 steps per BK=128
            const int c0 = s * 4 + h * 2;  // logical 16B chunk of this k-half
            i32x8 af[2], bf[2];
#pragma unroll
            for (int si = 0; si < 2; si++) {
                const unsigned char* base = sA + (wr * 64 + si * 32 + m) * 128;
                i32x4 lo = *(const i32x4*)(base + ((c0 ^ e) * 16));
                i32x4 hi = *(const i32x4*)(base + (((c0 + 1) ^ e) * 16));
                af[si] = __builtin_shufflevector(lo, hi, 0, 1, 2, 3, 4, 5, 6, 7);
            }
#pragma unroll
            for (int sj = 0; sj < 2; sj++) {
                const unsigned char* base = sB + (wc * 64 + sj * 32 + m) * 128;
                i32x4 lo = *(const i32x4*)(base + ((c0 ^ e) * 16));
                i32x4 hi = *(const i32x4*)(base + (((c0 + 1) ^ e) * 16));
                bf[sj] = __builtin_shufflevector(lo, hi, 0, 1, 2, 3, 4, 5, 6, 7);
            }
#pragma unroll
            for (int si = 0; si < 2; si++)
#pragma unroll
                for (int sj = 0; sj < 2; sj++)
                    acc[si][sj] = __builtin_amdgcn_mfma_scale_f32_32x32x64_f8f6f4(
                        af[si], bf[sj], acc[si][sj], 0 /*A fmt fp8*/,
                        0 /*B fmt fp8*/, 0, 127 /*scale A = 2^0*/,
                        0, 127 /*scale B = 2^0*/);
        }
        __syncthreads();  // protect single buffer before restage
    }

    // Epilogue: ROW-side only (full G). C/D: col (within subtile) = m,
    // row64 (within wave's 64 rows) = si*32 + (reg&3) + 8*(reg>>2) + 4*h.
#pragma unroll
    for (int si = 0; si < 2; si++)
#pragma unroll
        for (int reg = 0; reg < 16; reg++) {
            const int row64 = si * 32 + (reg & 3) + 8 * (reg >> 2) + 4 * h;
            const int rIdx = wr * 64 + row64;  // row within block tile
            const int yr = sYr[rIdx];
            const float nr = sNr[rIdx];
            float dp = -1.0f, dn = BIGF;
#pragma unroll
            for (int sj = 0; sj < 2; sj++) {
                const int cIdx = wc * 64 + sj * 32 + m;
                float d2 = nr + sNc[cIdx] - 2.0f * acc[si][sj][reg];
                float d = sqrtf(fmaxf(d2, 0.0f));
                bool same = (yr == sYc[cIdx]);
                dp = fmaxf(dp, same ? d : -1.0f);
                dn = fminf(dn, same ? BIGF : d);
            }
            // Reduce over the 32 col-lanes (offsets 1..16 keep h fixed).
            for (int off = 1; off < 32; off <<= 1) {
                dp = fmaxf(dp, __shfl_xor(dp, off, 64));
                dn = fminf(dn, __shfl_xor(dn, off, 64));
            }
            if (m == 0) {  // lanes 0 (h=0) and 32 (h=1): disjoint row64 sets
                redmax[wave][row64] = dp;
                redmin[wave][row64] = dn;
            }
        }
    __syncthreads();

    // Combine the two wc waves of each wr half; one atomic pair per row.
    // Non-negative floats: uint cmp == float cmp; clamp max to 0 (true
    // dist_ap >= 0 via the diagonal self-pair).
    if (tid < 128) {
        const int wr2 = tid >> 6, r64 = tid & 63;
        float mx = fmaxf(redmax[wr2 * 2][r64], redmax[wr2 * 2 + 1][r64]);
        float mn = fminf(redmin[wr2 * 2][r64], redmin[wr2 * 2 + 1][r64]);
        atomicMax(&ap[rowBase + tid], __float_as_uint(fmaxf(mx, 0.0f)));
        atomicMin(&an[rowBase + tid], __float_as_uint(mn));
    }

    // Last block computes the loss (release fence before counter increment;
    // acquire fence + agent-scope atomic loads in the last block).
    __syncthreads();
    if (tid == 0) {
        __threadfence();
        s_done = atomicAdd(cnt, 1u);
    }
    __syncthreads();
    if (s_done == gridDim.x - 1) {
        __threadfence();
        float s = 0.0f;
        for (int i = tid; i < N; i += 256) {
            unsigned ua = __hip_atomic_load(&ap[i], __ATOMIC_RELAXED,
                                            __HIP_MEMORY_SCOPE_AGENT);
            unsigned ub = __hip_atomic_load(&an[i], __ATOMIC_RELAXED,
                                            __HIP_MEMORY_SCOPE_AGENT);
            s += fmaxf(__uint_as_float(ua) - __uint_as_float(ub) + MARGIN, 0.0f);
        }
        for (int off = 32; off > 0; off >>= 1) s += __shfl_xor(s, off, 64);
        if (lane == 0) lsum[wave] = s;
        __syncthreads();
        if (tid == 0)
            out[0] = (lsum[0] + lsum[1] + lsum[2] + lsum[3]) / (float)N;
    }
}

extern "C" void kernel_launch(void* const* d_in, const int* in_sizes, int n_in,
                              void* d_out, int out_size, void* d_ws, size_t ws_size,
                              hipStream_t stream) {
    const float* X = (const float*)d_in[0];
    const int* Y = (const int*)d_in[1];
    float* out = (float*)d_out;
    const int N = in_sizes[1];          // 4096
    const int K = in_sizes[0] / N;      // 2048

    char* ws = (char*)d_ws;
    unsigned char* Xq = (unsigned char*)ws;                         // N*K bytes
    float* nrm = (float*)(ws + (size_t)N * K);
    unsigned* ap = (unsigned*)((char*)nrm + (size_t)N * 4);
    unsigned* an = (unsigned*)((char*)ap + (size_t)N * 4);
    unsigned* cnt = (unsigned*)((char*)an + (size_t)N * 4);

    convert_norm_kernel<<<N / 4, 256, 0, stream>>>(X, Xq, nrm, ap, an, cnt, K);
    const int NB = N / 128;
    gemm_reduce_kernel<<<NB * NB, 256, 0, stream>>>(Xq, nrm, Y, ap, an, cnt,
                                                    out, N, K);
}